// Round 3
// baseline (2968.936 us; speedup 1.0000x reference)
//
#include <hip/hip_runtime.h>
#include <math.h>

#define NB 32

__device__ __forceinline__ float softplus_f(float v) {
    return v > 0.f ? v + log1pf(expf(-v)) : log1pf(expf(v));
}

// p points at this row's 97 spline params in LDS (exclusively owned here).
// Overwrites p[0..63] with normalized bin widths/heights as scratch.
__device__ float rqs_eval(float x, float* p) {
    const float RMIN = -3.0f;
    const float total = 6.0f - 32.0f * 1e-5f;     // (RANGE - N_BINS*MIN_BIN)
    const float OFF = 0.54130903f;                // log(exp(1-1e-5)-1)

    float mw = -INFINITY, mh = -INFINITY;
    #pragma unroll
    for (int i = 0; i < NB; ++i) {
        mw = fmaxf(mw, p[i]);
        mh = fmaxf(mh, p[NB + i]);
    }
    float swd = 0.f, shd = 0.f;
    #pragma unroll
    for (int i = 0; i < NB; ++i) {
        swd += expf(p[i] - mw);
        shd += expf(p[NB + i] - mh);
    }
    float sw_scale = total / swd;
    float sh_scale = total / shd;

    // normalize widths/heights in place; bin search via cumsum of widths
    float cumw = 0.f;
    int cnt = 0;
    #pragma unroll
    for (int i = 0; i < NB; ++i) {
        float wi = expf(p[i] - mw) * sw_scale + 1e-5f;
        p[i] = wi;
        cumw += wi;
        cnt += (x >= RMIN + cumw) ? 1 : 0;
        float hi = expf(p[NB + i] - mh) * sh_scale + 1e-5f;
        p[NB + i] = hi;
    }
    // idx = clip(sum(x >= xpos)-1, 0, 31); xpos_0 = -3 contributes the -1
    int idx = cnt < 31 ? cnt : 31;

    float cw = 0.f, ch = 0.f;
    #pragma unroll
    for (int i = 0; i < NB; ++i) {
        if (i < idx) { cw += p[i]; ch += p[NB + i]; }
    }
    float wk = p[idx], hk = p[NB + idx];
    float dk  = softplus_f(p[2 * NB + idx] + OFF) + 1e-5f;
    float dk1 = softplus_f(p[2 * NB + idx + 1] + OFF) + 1e-5f;

    float xk = RMIN + cw, yk = RMIN + ch;
    float z = (x - xk) / wk;
    z = fminf(fmaxf(z, 0.f), 1.f);
    float s = hk / wk;
    float z1 = z * (1.f - z);
    float num = hk * (s * z * z + dk * z1);
    float den = s + (dk1 + dk - 2.f * s) * z1;
    float y = yk + num / den;
    return (x < -3.0f || x > 3.0f) ? x : y;
}

__global__ __launch_bounds__(256) void condflow_kernel(
    const float* __restrict__ cond, const float* __restrict__ t_in,
    const float* __restrict__ w1, const float* __restrict__ b1,
    const float* __restrict__ w2, const float* __restrict__ b2,
    const float* __restrict__ sw, const float* __restrict__ sb,
    const float* __restrict__ aw, const float* __restrict__ ab,
    float* __restrict__ out)
{
    __shared__ float lat[64][260];    // latent1 then latent2 (row stride 260: 16B aligned, conflict-benign)
    __shared__ float wsh[32][264];    // weight k-chunk staging
    __shared__ float pbuf[64][104];   // cond tile (G1), then per-layer spline params
    __shared__ float sa_s[64][4];
    __shared__ float x_s[64];

    const int t = threadIdx.x;
    const int row0 = blockIdx.x * 64;

    // ---- stage cond tile [64][64] into pbuf ----
    #pragma unroll
    for (int it = 0; it < 4; ++it) {
        int idx = it * 256 + t;            // 0..1023 float4s
        int r = idx >> 4;
        int kv = idx & 15;
        float4 v = *reinterpret_cast<const float4*>(cond + (size_t)(row0 + r) * 64 + kv * 4);
        *reinterpret_cast<float4*>(&pbuf[r][kv * 4]) = v;
    }
    __syncthreads();

    const int tr = t >> 5;      // 0..7  -> rows tr*8..+7
    const int tc = t & 31;      // 0..31 -> cols tc*8..+7
    const int r0 = tr * 8;
    const int c0 = tc * 8;

    // ---- GEMM1: lat = relu(cond @ w1 + b1), K=64 ----
    {
        float acc[8][8];
        #pragma unroll
        for (int j = 0; j < 8; ++j)
            #pragma unroll
            for (int i = 0; i < 8; ++i) acc[j][i] = 0.f;

        for (int kc = 0; kc < 2; ++kc) {
            __syncthreads();
            #pragma unroll
            for (int it = 0; it < 8; ++it) {
                int idx = it * 256 + t;    // 2048 float4s = 32x256 floats
                int kk = idx >> 6;
                int cv = idx & 63;
                float4 v = *reinterpret_cast<const float4*>(w1 + (size_t)(kc * 32 + kk) * 256 + cv * 4);
                *reinterpret_cast<float4*>(&wsh[kk][cv * 4]) = v;
            }
            __syncthreads();
            #pragma unroll 4
            for (int kk = 0; kk < 32; ++kk) {
                int k = kc * 32 + kk;
                float a[8];
                #pragma unroll
                for (int j = 0; j < 8; ++j) a[j] = pbuf[r0 + j][k];
                float wv[8];
                *reinterpret_cast<float4*>(&wv[0]) = *reinterpret_cast<const float4*>(&wsh[kk][c0]);
                *reinterpret_cast<float4*>(&wv[4]) = *reinterpret_cast<const float4*>(&wsh[kk][c0 + 4]);
                #pragma unroll
                for (int j = 0; j < 8; ++j)
                    #pragma unroll
                    for (int i = 0; i < 8; ++i)
                        acc[j][i] = fmaf(a[j], wv[i], acc[j][i]);
            }
        }
        __syncthreads();
        #pragma unroll
        for (int j = 0; j < 8; ++j)
            #pragma unroll
            for (int i = 0; i < 8; ++i)
                lat[r0 + j][c0 + i] = fmaxf(acc[j][i] + b1[c0 + i], 0.f);
    }

    // ---- GEMM2: lat = relu(lat @ w2 + b2), K=256 ----
    {
        float acc[8][8];
        #pragma unroll
        for (int j = 0; j < 8; ++j)
            #pragma unroll
            for (int i = 0; i < 8; ++i) acc[j][i] = 0.f;

        for (int kc = 0; kc < 8; ++kc) {
            __syncthreads();
            #pragma unroll
            for (int it = 0; it < 8; ++it) {
                int idx = it * 256 + t;
                int kk = idx >> 6;
                int cv = idx & 63;
                float4 v = *reinterpret_cast<const float4*>(w2 + (size_t)(kc * 32 + kk) * 256 + cv * 4);
                *reinterpret_cast<float4*>(&wsh[kk][cv * 4]) = v;
            }
            __syncthreads();
            #pragma unroll 4
            for (int kk = 0; kk < 32; ++kk) {
                int k = kc * 32 + kk;
                float a[8];
                #pragma unroll
                for (int j = 0; j < 8; ++j) a[j] = lat[r0 + j][k];
                float wv[8];
                *reinterpret_cast<float4*>(&wv[0]) = *reinterpret_cast<const float4*>(&wsh[kk][c0]);
                *reinterpret_cast<float4*>(&wv[4]) = *reinterpret_cast<const float4*>(&wsh[kk][c0 + 4]);
                #pragma unroll
                for (int j = 0; j < 8; ++j)
                    #pragma unroll
                    for (int i = 0; i < 8; ++i)
                        acc[j][i] = fmaf(a[j], wv[i], acc[j][i]);
            }
        }
        __syncthreads();   // all lat reads done before in-place overwrite
        #pragma unroll
        for (int j = 0; j < 8; ++j)
            #pragma unroll
            for (int i = 0; i < 8; ++i)
                lat[r0 + j][c0 + i] = fmaxf(acc[j][i] + b2[c0 + i], 0.f);
    }
    __syncthreads();

    // ---- sa = lat @ aff_w + aff_b (cols 0..3), then x0 = t*exp(sa1)+sa0 ----
    {
        float* wa = &wsh[0][0];            // flat [256*4]
        #pragma unroll
        for (int i = 0; i < 4; ++i) wa[i * 256 + t] = aw[i * 256 + t];
        __syncthreads();
        const int rr = t >> 2;
        const int cc = t & 3;
        float s = 0.f;
        for (int k = 0; k < 256; k += 4) {
            float4 a4 = *reinterpret_cast<const float4*>(&lat[rr][k]);
            s = fmaf(a4.x, wa[(k + 0) * 4 + cc], s);
            s = fmaf(a4.y, wa[(k + 1) * 4 + cc], s);
            s = fmaf(a4.z, wa[(k + 2) * 4 + cc], s);
            s = fmaf(a4.w, wa[(k + 3) * 4 + cc], s);
        }
        sa_s[rr][cc] = s + ab[cc];
    }
    __syncthreads();
    if (t < 64) {
        float x = t_in[row0 + t] * expf(sa_s[t][1]) + sa_s[t][0];
        x_s[t] = x;
    }
    __syncthreads();

    // ---- spline layers, chain applies last layer first ----
    const int trp = t / 13;                // rows trp*4..+3 (valid for t<208)
    const int tcp = t - trp * 13;          // cols tcp*8..+7 (97 padded to 104)
    const bool pact = (t < 208);
    const int rp0 = trp * 4;
    const int cp0 = tcp * 8;

    for (int l = 3; l >= 0; --l) {
        float acc[4][8];
        #pragma unroll
        for (int j = 0; j < 4; ++j)
            #pragma unroll
            for (int i = 0; i < 8; ++i) acc[j][i] = 0.f;

        for (int kc = 0; kc < 8; ++kc) {
            __syncthreads();
            for (int idx = t; idx < 32 * 97; idx += 256) {
                int kk = idx / 97;
                int c = idx - kk * 97;
                wsh[kk][c] = sw[((size_t)l * 256 + kc * 32 + kk) * 97 + c];
            }
            __syncthreads();
            if (pact) {
                #pragma unroll 4
                for (int kk = 0; kk < 32; ++kk) {
                    int k = kc * 32 + kk;
                    float a[4];
                    #pragma unroll
                    for (int j = 0; j < 4; ++j) a[j] = lat[rp0 + j][k];
                    float wv[8];
                    *reinterpret_cast<float4*>(&wv[0]) = *reinterpret_cast<const float4*>(&wsh[kk][cp0]);
                    *reinterpret_cast<float4*>(&wv[4]) = *reinterpret_cast<const float4*>(&wsh[kk][cp0 + 4]);
                    #pragma unroll
                    for (int j = 0; j < 4; ++j)
                        #pragma unroll
                        for (int i = 0; i < 8; ++i)
                            acc[j][i] = fmaf(a[j], wv[i], acc[j][i]);
                }
            }
        }
        __syncthreads();
        if (pact) {
            #pragma unroll
            for (int j = 0; j < 4; ++j)
                #pragma unroll
                for (int i = 0; i < 8; ++i) {
                    int c = cp0 + i;
                    if (c < 97) pbuf[rp0 + j][c] = acc[j][i] + sb[l * 97 + c];
                }
        }
        __syncthreads();
        if ((t & 3) == 0) {
            int r = t >> 2;
            x_s[r] = rqs_eval(x_s[r], &pbuf[r][0]);
        }
        __syncthreads();
    }

    // ---- f2 affine + normal CDF ----
    if (t < 64) {
        float x = x_s[t];
        x = x * expf(sa_s[t][3]) + sa_s[t][2];
        out[row0 + t] = 0.5f * (1.0f + erff(x * 0.70710678118f));
    }
}

extern "C" void kernel_launch(void* const* d_in, const int* in_sizes, int n_in,
                              void* d_out, int out_size, void* d_ws, size_t ws_size,
                              hipStream_t stream) {
    const float* cond = (const float*)d_in[0];
    const float* t_in = (const float*)d_in[1];
    const float* w1   = (const float*)d_in[2];
    const float* b1   = (const float*)d_in[3];
    const float* w2   = (const float*)d_in[4];
    const float* b2   = (const float*)d_in[5];
    const float* sw   = (const float*)d_in[6];
    const float* sb   = (const float*)d_in[7];
    const float* aw   = (const float*)d_in[8];
    const float* ab   = (const float*)d_in[9];
    float* out = (float*)d_out;

    const int B = out_size;            // 262144
    const int nblocks = B / 64;
    condflow_kernel<<<dim3(nblocks), dim3(256), 0, stream>>>(
        cond, t_in, w1, b1, w2, b2, sw, sb, aw, ab, out);
}